// Round 1
// baseline (233.720 us; speedup 1.0000x reference)
//
#include <hip/hip_runtime.h>

#define NB   4
#define NROW 4096      // W*W
#define CIN  256
#define OUTC 512

typedef __bf16 bf16x8 __attribute__((ext_vector_type(8)));
typedef float  f32x4  __attribute__((ext_vector_type(4)));

__device__ __forceinline__ ushort f2bf(float x) {
  union { float f; unsigned u; } v; v.f = x;
  unsigned r = v.u + 0x7fffu + ((v.u >> 16) & 1u);   // RNE
  return (ushort)(r >> 16);
}

// ---------------------------------------------------------------------------
// Projections: g = x @ g_w  (y==0), f = h @ f_w (y==1); store bf16 into the
// upper-channel scratch region of out: row slot = out + row*512 + 256,
// g at ushort [0..31], f at ushort [32..63].
// ---------------------------------------------------------------------------
__global__ __launch_bounds__(256) void proj_kernel(
    const float* __restrict__ x, const float* __restrict__ h,
    const float* __restrict__ fw, const float* __restrict__ gw,
    float* __restrict__ out) {
  __shared__ float wl[256 * 32];
  __shared__ float rows[8][260];
  const int t = threadIdx.x;
  const int which = blockIdx.y;               // 0 -> g, 1 -> f
  const float* in = which ? h : x;
  const float* w  = which ? fw : gw;
  for (int i = t; i < 8192; i += 256) wl[i] = w[i];
  const int row0 = blockIdx.x * 32;
  const int d = t & 31, rl = t >> 5;
  for (int rp = 0; rp < 4; ++rp) {
    __syncthreads();
    for (int i = t; i < 2048; i += 256)
      rows[i >> 8][i & 255] = in[(long)(row0 + rp * 8 + (i >> 8)) * CIN + (i & 255)];
    __syncthreads();
    float a = 0.f;
#pragma unroll 8
    for (int c = 0; c < 256; ++c) a = fmaf(rows[rl][c], wl[c * 32 + d], a);
    const long row = row0 + rp * 8 + rl;
    ((ushort*)(out + row * OUTC + 256))[which * 32 + d] = f2bf(a);
  }
}

// ---------------------------------------------------------------------------
// Flash attention. 256 blocks x 256 threads. Each wave: 16 q rows x 256 ch.
// Fragment layouts (verified, guide §3): A: row=l&15, k=8*(l>>4)+j (8 contig);
// B: col=l&15, k=8*(l>>4)+j; D: col=l&15, row=4*(l>>4)+reg.
// ---------------------------------------------------------------------------
__global__ __launch_bounds__(256) void attn_kernel(
    const float* __restrict__ h, float* __restrict__ out) {
  __shared__ alignas(16) ushort Vt[256][72];     // V^T tile, [c][key], pad 72
  __shared__ alignas(16) ushort Pl[4][16][72];   // per-wave P, [q][key]

  const int t  = threadIdx.x;
  const int w  = t >> 6;
  const int l  = t & 63;
  const int lo = l & 15;
  const int hi = l >> 4;

  // XCD-aware remap: batch pinned to an XCD pair (bid%8 selects XCD).
  const int bid = blockIdx.x;
  const int b   = (bid >> 1) & 3;
  const int qb  = ((bid >> 3) << 1) | (bid & 1);
  const int q0  = qb * 64;
  const long rowbase = (long)b * NROW;

  // Q fragment (row q0 + w*16 + lo, 8 contiguous bf16 at k = hi*8)
  const ushort* gslot = (const ushort*)(out + (rowbase + q0 + w * 16 + lo) * OUTC + 256);
  const bf16x8 qf = *(const bf16x8*)(gslot + hi * 8);

  f32x4 acc[16];
#pragma unroll
  for (int i = 0; i < 16; ++i) acc[i] = (f32x4){0.f, 0.f, 0.f, 0.f};
  float mrow[4] = {-1e30f, -1e30f, -1e30f, -1e30f};
  float lsum[4] = {0.f, 0.f, 0.f, 0.f};

  for (int k0 = 0; k0 < NROW; k0 += 64) {
    // K fragments (global, no LDS dependency) — issue before the barrier
    bf16x8 kf[4];
#pragma unroll
    for (int kt = 0; kt < 4; ++kt) {
      const ushort* fslot =
          (const ushort*)(out + (rowbase + k0 + kt * 16 + lo) * OUTC + 256) + 32;
      kf[kt] = *(const bf16x8*)(fslot + hi * 8);
    }

    __syncthreads();   // previous tile's Vt reads complete
    {   // stage V^T: Vt[c][key] = bf16(h[b][k0+key][c]); c = t (coalesced reads)
      const float* hp = h + (rowbase + k0) * CIN + t;
#pragma unroll
      for (int g8 = 0; g8 < 8; ++g8) {
        ushort tmp[8];
#pragma unroll
        for (int i = 0; i < 8; ++i) tmp[i] = f2bf(hp[(g8 * 8 + i) * CIN]);
        *(bf16x8*)&Vt[t][g8 * 8] = *(const bf16x8*)tmp;   // 16B write
      }
    }
    __syncthreads();

    // S = Q K^T : 4 MFMA (full K since Dp=32)
    f32x4 sv[4];
#pragma unroll
    for (int kt = 0; kt < 4; ++kt)
      sv[kt] = __builtin_amdgcn_mfma_f32_16x16x32_bf16(
          qf, kf[kt], (f32x4){0.f, 0.f, 0.f, 0.f}, 0, 0, 0);

    // online softmax (rows spread over the 16-lane nibble; q = 4*hi + r)
    float alpha[4];
    bool upd = false;
#pragma unroll
    for (int r = 0; r < 4; ++r) {
      float m4 = fmaxf(fmaxf(sv[0][r], sv[1][r]), fmaxf(sv[2][r], sv[3][r]));
#pragma unroll
      for (int off = 1; off < 16; off <<= 1) m4 = fmaxf(m4, __shfl_xor(m4, off, 64));
      const float mn = fmaxf(mrow[r], m4);
      alpha[r] = __expf(mrow[r] - mn);
      upd |= (mn > mrow[r]);
      mrow[r] = mn;
    }
    if (__any(upd)) {          // defer-rescale: skip when no row max moved
#pragma unroll
      for (int ct = 0; ct < 16; ++ct)
#pragma unroll
        for (int r = 0; r < 4; ++r) acc[ct][r] *= alpha[r];
#pragma unroll
      for (int r = 0; r < 4; ++r) lsum[r] *= alpha[r];
    }
#pragma unroll
    for (int r = 0; r < 4; ++r) {
      float ps = 0.f;
#pragma unroll
      for (int kt = 0; kt < 4; ++kt) {
        const float p = __expf(sv[kt][r] - mrow[r]);
        sv[kt][r] = p;
        ps += p;
      }
#pragma unroll
      for (int off = 1; off < 16; off <<= 1) ps += __shfl_xor(ps, off, 64);
      lsum[r] += ps;
    }

    // P -> LDS (bf16), D-layout -> A-layout transpose through LDS
#pragma unroll
    for (int kt = 0; kt < 4; ++kt)
#pragma unroll
      for (int r = 0; r < 4; ++r)
        Pl[w][hi * 4 + r][kt * 16 + lo] = f2bf(sv[kt][r]);

    asm volatile("s_waitcnt lgkmcnt(0)" ::: "memory");

    const bf16x8 pa0 = *(const bf16x8*)&Pl[w][lo][hi * 8];
    const bf16x8 pa1 = *(const bf16x8*)&Pl[w][lo][32 + hi * 8];
#pragma unroll
    for (int ct = 0; ct < 16; ++ct) {
      const bf16x8 v0 = *(const bf16x8*)&Vt[ct * 16 + lo][hi * 8];
      const bf16x8 v1 = *(const bf16x8*)&Vt[ct * 16 + lo][32 + hi * 8];
      acc[ct] = __builtin_amdgcn_mfma_f32_16x16x32_bf16(pa0, v0, acc[ct], 0, 0, 0);
      acc[ct] = __builtin_amdgcn_mfma_f32_16x16x32_bf16(pa1, v1, acc[ct], 0, 0, 0);
    }
  }

  // epilogue: normalize and store o into channels [0,256)
#pragma unroll
  for (int r = 0; r < 4; ++r) {
    const float inv = 1.f / lsum[r];
    float* orow = out + (rowbase + q0 + w * 16 + hi * 4 + r) * OUTC;
#pragma unroll
    for (int ct = 0; ct < 16; ++ct) orow[ct * 16 + lo] = acc[ct][r] * inv;
  }
}

// ---------------------------------------------------------------------------
// Concat: out[..., 256:512] = x  (runs last; reclaims the scratch region)
// ---------------------------------------------------------------------------
__global__ __launch_bounds__(256) void concat_kernel(
    const float4* __restrict__ x, float4* __restrict__ out) {
  const int idx = blockIdx.x * 256 + threadIdx.x;   // 16384*64 float4
  const int row = idx >> 6, c4 = idx & 63;
  out[row * 128 + 64 + c4] = x[idx];
}

extern "C" void kernel_launch(void* const* d_in, const int* in_sizes, int n_in,
                              void* d_out, int out_size, void* d_ws, size_t ws_size,
                              hipStream_t stream) {
  const float* x  = (const float*)d_in[0];
  const float* h  = (const float*)d_in[1];
  const float* fw = (const float*)d_in[2];
  const float* gw = (const float*)d_in[3];
  float* out = (float*)d_out;

  proj_kernel<<<dim3(512, 2), 256, 0, stream>>>(x, h, fw, gw, out);
  attn_kernel<<<256, 256, 0, stream>>>(h, out);
  concat_kernel<<<4096, 256, 0, stream>>>((const float4*)x, (float4*)out);
}

// Round 2
// 156.365 us; speedup vs baseline: 1.4947x; 1.4947x over previous
//
#include <hip/hip_runtime.h>

#define NB   4
#define NROW 4096      // W*W
#define CIN  256
#define OUTC 512
#define DP   32

typedef __bf16 bf16x8 __attribute__((ext_vector_type(8)));
typedef float  f32x4  __attribute__((ext_vector_type(4)));
typedef ushort ushort8 __attribute__((ext_vector_type(8)));

__device__ __forceinline__ ushort f2bf(float x) {
  union { float f; unsigned u; } v; v.f = x;
  unsigned r = v.u + 0x7fffu + ((v.u >> 16) & 1u);   // RNE
  return (ushort)(r >> 16);
}

__device__ __forceinline__ void gload_lds16(const void* g, void* l) {
  __builtin_amdgcn_global_load_lds(
      (const __attribute__((address_space(1))) unsigned int*)g,
      (__attribute__((address_space(3))) unsigned int*)l, 16, 0, 0);
}

// ===========================================================================
// SPLIT-K PATH (uses d_ws)
// ===========================================================================

// Projections -> bf16 in ws. which==0: g = x@g_w -> Qb ; which==1: f = h@f_w -> Kb
__global__ __launch_bounds__(256) void proj_ws(
    const float* __restrict__ x, const float* __restrict__ h,
    const float* __restrict__ fw, const float* __restrict__ gw,
    ushort* __restrict__ Qb, ushort* __restrict__ Kb) {
  __shared__ float wl[256 * 32];
  __shared__ float rows[8][260];
  const int t = threadIdx.x;
  const int which = blockIdx.y;
  const float* in = which ? h : x;
  const float* w  = which ? fw : gw;
  ushort* dst = which ? Kb : Qb;
  for (int i = t; i < 8192; i += 256) wl[i] = w[i];
  const int row0 = blockIdx.x * 32;
  const int d = t & 31, rl = t >> 5;
  for (int rp = 0; rp < 4; ++rp) {
    __syncthreads();
    for (int i = t; i < 2048; i += 256)
      rows[i >> 8][i & 255] = in[(long)(row0 + rp * 8 + (i >> 8)) * CIN + (i & 255)];
    __syncthreads();
    float a = 0.f;
#pragma unroll 8
    for (int c = 0; c < 256; ++c) a = fmaf(rows[rl][c], wl[c * 32 + d], a);
    const long row = row0 + rp * 8 + rl;
    dst[row * DP + d] = f2bf(a);
  }
}

// V prep: bf16, transposed, tile-major, group-swizzled.
// Vws[b][tile][c][64 keys] where key-group g sits at position g ^ (c&7).
__global__ __launch_bounds__(256) void vprep(
    const float* __restrict__ h, ushort* __restrict__ Vws) {
  const int t = threadIdx.x;
  const int b = blockIdx.x >> 6, tile = blockIdx.x & 63;
  const int c = t;
  const float* hp = h + (size_t)(b * NROW + tile * 64) * CIN + c;
  ushort* dst = Vws + ((size_t)(b * 64 + tile) * 256 + c) * 64;
#pragma unroll
  for (int grp = 0; grp < 8; ++grp) {
    ushort tmp[8];
#pragma unroll
    for (int j = 0; j < 8; ++j) tmp[j] = f2bf(hp[(grp * 8 + j) * CIN]);
    *(ushort8*)(dst + (((grp ^ (c & 7)) << 3))) = *(const ushort8*)tmp;
  }
}

// Flash attention, split-K partials.
// Layouts (16x16x32 bf16, verified r1): A row=l&15,k=8*(l>>4)+j ;
// B col=l&15,k=8*(l>>4)+j ; D col=l&15,row=4*(l>>4)+reg.
__global__ __launch_bounds__(256, 4) void attn_split(
    const ushort* __restrict__ Qb, const ushort* __restrict__ Kb,
    const ushort* __restrict__ Vws, float* __restrict__ pml,
    ushort* __restrict__ pacc, int nsplit, int tiles) {
  __shared__ ushort Vt[16384];   // 32KB  [c][64] group-swizzled
  __shared__ ushort Pl[4096];    // 8KB   per-wave [16][64] group-swizzled

  const int t  = threadIdx.x;
  const int w  = t >> 6;
  const int l  = t & 63;
  const int lo = l & 15;
  const int hi = l >> 4;

  const int bid = blockIdx.x;
  const int n4  = nsplit * 4;
  const int qb  = bid / n4;
  const int rem = bid % n4;
  const int b   = rem / nsplit;
  const int s   = rem % nsplit;
  const int q0  = qb * 64;

  const bf16x8 qf =
      *(const bf16x8*)(Qb + (size_t)(b * NROW + q0 + w * 16 + lo) * DP + hi * 8);

  f32x4 acc[16];
#pragma unroll
  for (int i = 0; i < 16; ++i) acc[i] = (f32x4){0.f, 0.f, 0.f, 0.f};
  float mrow[4] = {-1e30f, -1e30f, -1e30f, -1e30f};
  float lsum[4] = {0.f, 0.f, 0.f, 0.f};

  ushort* plw = Pl + w * 1024;

  for (int tt = 0; tt < tiles; ++tt) {
    const int tileIdx = s * tiles + tt;
    const int k0 = tileIdx * 64;

    // S = Q K^T (kf loads issued before the staging loads -> vmcnt order ok)
    f32x4 sv[4];
#pragma unroll
    for (int kt = 0; kt < 4; ++kt) {
      const bf16x8 kf = *(const bf16x8*)(Kb + (size_t)(b * NROW + k0 + kt * 16 + lo) * DP + hi * 8);
      sv[kt] = __builtin_amdgcn_mfma_f32_16x16x32_bf16(
          qf, kf, (f32x4){0.f, 0.f, 0.f, 0.f}, 0, 0, 0);
    }

    __syncthreads();   // prev tile's Vt/Pl reads complete
    {  // stage V tile: straight async memcpy (data pre-swizzled in ws)
      const ushort* src = Vws + (size_t)(b * 64 + tileIdx) * 16384;
#pragma unroll
      for (int i = 0; i < 8; ++i) {
        const int chunk = (w * 8 + i) * 512;          // ushorts, 1KB per chunk
        gload_lds16(src + chunk + l * 8, &Vt[chunk]); // lds dest: base + lane*16
      }
    }

    // online softmax (q = 4*hi + r, keys spread over lo)
    float alpha[4];
    bool upd = false;
#pragma unroll
    for (int r = 0; r < 4; ++r) {
      float m4 = fmaxf(fmaxf(sv[0][r], sv[1][r]), fmaxf(sv[2][r], sv[3][r]));
#pragma unroll
      for (int off = 1; off < 16; off <<= 1) m4 = fmaxf(m4, __shfl_xor(m4, off, 64));
      const float mn = fmaxf(mrow[r], m4);
      alpha[r] = __expf(mrow[r] - mn);
      upd |= (mn > mrow[r]);
      mrow[r] = mn;
    }
    if (__any(upd)) {
#pragma unroll
      for (int ct = 0; ct < 16; ++ct)
#pragma unroll
        for (int r = 0; r < 4; ++r) acc[ct][r] *= alpha[r];
#pragma unroll
      for (int r = 0; r < 4; ++r) lsum[r] *= alpha[r];
    }
#pragma unroll
    for (int r = 0; r < 4; ++r) {
      float ps = 0.f;
#pragma unroll
      for (int kt = 0; kt < 4; ++kt) {
        const float p = __expf(sv[kt][r] - mrow[r]);
        sv[kt][r] = p;
        ps += p;
      }
#pragma unroll
      for (int off = 1; off < 16; off <<= 1) ps += __shfl_xor(ps, off, 64);
      lsum[r] += ps;
    }

    // P -> LDS bf16, swizzled: key kt*16+lo -> grp = kt*2+(lo>>3), j = lo&7
#pragma unroll
    for (int kt = 0; kt < 4; ++kt) {
      const int grp = kt * 2 + (lo >> 3);
#pragma unroll
      for (int r = 0; r < 4; ++r) {
        const int q = hi * 4 + r;
        plw[q * 64 + ((grp ^ (q & 7)) << 3) + (lo & 7)] = f2bf(sv[kt][r]);
      }
    }

    __syncthreads();   // Vt staged (vmcnt drained) + Pl visible

    // PV
    const bf16x8 pa0 = *(const bf16x8*)&plw[lo * 64 + ((hi ^ (lo & 7)) << 3)];
    const bf16x8 pa1 = *(const bf16x8*)&plw[lo * 64 + (((hi + 4) ^ (lo & 7)) << 3)];
#pragma unroll
    for (int ct = 0; ct < 16; ++ct) {
      const int c = ct * 16 + lo;
      const bf16x8 v0 = *(const bf16x8*)&Vt[c * 64 + ((hi ^ (c & 7)) << 3)];
      const bf16x8 v1 = *(const bf16x8*)&Vt[c * 64 + (((hi + 4) ^ (c & 7)) << 3)];
      acc[ct] = __builtin_amdgcn_mfma_f32_16x16x32_bf16(pa0, v0, acc[ct], 0, 0, 0);
      acc[ct] = __builtin_amdgcn_mfma_f32_16x16x32_bf16(pa1, v1, acc[ct], 0, 0, 0);
    }
  }

  // store partials: pacc bf16 [row][split][256], pml f32 [row][split][2]
  const int rowg = b * NROW + q0 + w * 16;
#pragma unroll
  for (int r = 0; r < 4; ++r) {
    const int q = hi * 4 + r;
    if (lo == 0) {
      float* mlp = pml + ((size_t)(rowg + q) * nsplit + s) * 2;
      mlp[0] = mrow[r];
      mlp[1] = lsum[r];
    }
    ushort* pr = pacc + ((size_t)(rowg + q) * nsplit + s) * 256;
#pragma unroll
    for (int ct = 0; ct < 16; ++ct) pr[ct * 16 + lo] = f2bf(acc[ct][r]);
  }
}

// Combine partials + normalize -> out[...,0:256]; concat x -> out[...,256:512]
__global__ __launch_bounds__(256) void reduce_concat(
    const float* __restrict__ pml, const ushort* __restrict__ pacc,
    const float* __restrict__ x, float* __restrict__ out, int nsplit) {
  const int t = threadIdx.x;
  const int row = blockIdx.x * 8 + (t >> 5);
  const int c0 = (t & 31) * 8;

  float ms[4], ls[4];
  float m = -1e30f;
  for (int s = 0; s < nsplit; ++s) {
    ms[s] = pml[((size_t)row * nsplit + s) * 2];
    ls[s] = pml[((size_t)row * nsplit + s) * 2 + 1];
    m = fmaxf(m, ms[s]);
  }
  float L = 0.f, wgt[4];
  for (int s = 0; s < nsplit; ++s) {
    wgt[s] = __expf(ms[s] - m);
    L += wgt[s] * ls[s];
  }
  float o[8] = {0.f, 0.f, 0.f, 0.f, 0.f, 0.f, 0.f, 0.f};
  for (int s = 0; s < nsplit; ++s) {
    const bf16x8 a = *(const bf16x8*)(pacc + ((size_t)row * nsplit + s) * 256 + c0);
    const float wg = wgt[s];
#pragma unroll
    for (int i = 0; i < 8; ++i) o[i] += wg * (float)a[i];
  }
  const float inv = 1.f / L;
  float4 o0 = {o[0] * inv, o[1] * inv, o[2] * inv, o[3] * inv};
  float4 o1 = {o[4] * inv, o[5] * inv, o[6] * inv, o[7] * inv};
  float4* op = (float4*)(out + (size_t)row * OUTC + c0);
  op[0] = o0; op[1] = o1;
  // concat
  const float4* xp = (const float4*)(x + (size_t)row * CIN + c0);
  float4* oc = (float4*)(out + (size_t)row * OUTC + 256 + c0);
  oc[0] = xp[0]; oc[1] = xp[1];
}

// ===========================================================================
// FALLBACK PATH (round-1, no workspace needed) — used if ws_size too small
// ===========================================================================
__global__ __launch_bounds__(256) void proj_fb(
    const float* __restrict__ x, const float* __restrict__ h,
    const float* __restrict__ fw, const float* __restrict__ gw,
    float* __restrict__ out) {
  __shared__ float wl[256 * 32];
  __shared__ float rows[8][260];
  const int t = threadIdx.x;
  const int which = blockIdx.y;
  const float* in = which ? h : x;
  const float* w  = which ? fw : gw;
  for (int i = t; i < 8192; i += 256) wl[i] = w[i];
  const int row0 = blockIdx.x * 32;
  const int d = t & 31, rl = t >> 5;
  for (int rp = 0; rp < 4; ++rp) {
    __syncthreads();
    for (int i = t; i < 2048; i += 256)
      rows[i >> 8][i & 255] = in[(long)(row0 + rp * 8 + (i >> 8)) * CIN + (i & 255)];
    __syncthreads();
    float a = 0.f;
#pragma unroll 8
    for (int c = 0; c < 256; ++c) a = fmaf(rows[rl][c], wl[c * 32 + d], a);
    const long row = row0 + rp * 8 + rl;
    ((ushort*)(out + row * OUTC + 256))[which * 32 + d] = f2bf(a);
  }
}

__global__ __launch_bounds__(256) void attn_fb(
    const float* __restrict__ h, float* __restrict__ out) {
  __shared__ alignas(16) ushort Vt[256][72];
  __shared__ alignas(16) ushort Pl[4][16][72];
  const int t = threadIdx.x;
  const int w = t >> 6, l = t & 63, lo = l & 15, hi = l >> 4;
  const int bid = blockIdx.x;
  const int b = (bid >> 1) & 3;
  const int qb = ((bid >> 3) << 1) | (bid & 1);
  const int q0 = qb * 64;
  const long rowbase = (long)b * NROW;
  const ushort* gslot = (const ushort*)(out + (rowbase + q0 + w * 16 + lo) * OUTC + 256);
  const bf16x8 qf = *(const bf16x8*)(gslot + hi * 8);
  f32x4 acc[16];
#pragma unroll
  for (int i = 0; i < 16; ++i) acc[i] = (f32x4){0.f, 0.f, 0.f, 0.f};
  float mrow[4] = {-1e30f, -1e30f, -1e30f, -1e30f};
  float lsum[4] = {0.f, 0.f, 0.f, 0.f};
  for (int k0 = 0; k0 < NROW; k0 += 64) {
    bf16x8 kf[4];
#pragma unroll
    for (int kt = 0; kt < 4; ++kt) {
      const ushort* fslot =
          (const ushort*)(out + (rowbase + k0 + kt * 16 + lo) * OUTC + 256) + 32;
      kf[kt] = *(const bf16x8*)(fslot + hi * 8);
    }
    __syncthreads();
    {
      const float* hp = h + (rowbase + k0) * CIN + t;
#pragma unroll
      for (int g8 = 0; g8 < 8; ++g8) {
        ushort tmp[8];
#pragma unroll
        for (int i = 0; i < 8; ++i) tmp[i] = f2bf(hp[(g8 * 8 + i) * CIN]);
        *(bf16x8*)&Vt[t][g8 * 8] = *(const bf16x8*)tmp;
      }
    }
    __syncthreads();
    f32x4 sv[4];
#pragma unroll
    for (int kt = 0; kt < 4; ++kt)
      sv[kt] = __builtin_amdgcn_mfma_f32_16x16x32_bf16(
          qf, kf[kt], (f32x4){0.f, 0.f, 0.f, 0.f}, 0, 0, 0);
    float alpha[4];
    bool upd = false;
#pragma unroll
    for (int r = 0; r < 4; ++r) {
      float m4 = fmaxf(fmaxf(sv[0][r], sv[1][r]), fmaxf(sv[2][r], sv[3][r]));
#pragma unroll
      for (int off = 1; off < 16; off <<= 1) m4 = fmaxf(m4, __shfl_xor(m4, off, 64));
      const float mn = fmaxf(mrow[r], m4);
      alpha[r] = __expf(mrow[r] - mn);
      upd |= (mn > mrow[r]);
      mrow[r] = mn;
    }
    if (__any(upd)) {
#pragma unroll
      for (int ct = 0; ct < 16; ++ct)
#pragma unroll
        for (int r = 0; r < 4; ++r) acc[ct][r] *= alpha[r];
#pragma unroll
      for (int r = 0; r < 4; ++r) lsum[r] *= alpha[r];
    }
#pragma unroll
    for (int r = 0; r < 4; ++r) {
      float ps = 0.f;
#pragma unroll
      for (int kt = 0; kt < 4; ++kt) {
        const float p = __expf(sv[kt][r] - mrow[r]);
        sv[kt][r] = p;
        ps += p;
      }
#pragma unroll
      for (int off = 1; off < 16; off <<= 1) ps += __shfl_xor(ps, off, 64);
      lsum[r] += ps;
    }
#pragma unroll
    for (int kt = 0; kt < 4; ++kt)
#pragma unroll
      for (int r = 0; r < 4; ++r)
        Pl[w][hi * 4 + r][kt * 16 + lo] = f2bf(sv[kt][r]);
    asm volatile("s_waitcnt lgkmcnt(0)" ::: "memory");
    const bf16x8 pa0 = *(const bf16x8*)&Pl[w][lo][hi * 8];
    const bf16x8 pa1 = *(const bf16x8*)&Pl[w][lo][32 + hi * 8];
#pragma unroll
    for (int ct = 0; ct < 16; ++ct) {
      const bf16x8 v0 = *(const bf16x8*)&Vt[ct * 16 + lo][hi * 8];
      const bf16x8 v1 = *(const bf16x8*)&Vt[ct * 16 + lo][32 + hi * 8];
      acc[ct] = __builtin_amdgcn_mfma_f32_16x16x32_bf16(pa0, v0, acc[ct], 0, 0, 0);
      acc[ct] = __builtin_amdgcn_mfma_f32_16x16x32_bf16(pa1, v1, acc[ct], 0, 0, 0);
    }
  }
#pragma unroll
  for (int r = 0; r < 4; ++r) {
    const float inv = 1.f / lsum[r];
    float* orow = out + (rowbase + q0 + w * 16 + hi * 4 + r) * OUTC;
#pragma unroll
    for (int ct = 0; ct < 16; ++ct) orow[ct * 16 + lo] = acc[ct][r] * inv;
  }
}

__global__ __launch_bounds__(256) void concat_fb(
    const float4* __restrict__ x, float4* __restrict__ out) {
  const int idx = blockIdx.x * 256 + threadIdx.x;
  const int row = idx >> 6, c4 = idx & 63;
  out[row * 128 + 64 + c4] = x[idx];
}

// ===========================================================================
extern "C" void kernel_launch(void* const* d_in, const int* in_sizes, int n_in,
                              void* d_out, int out_size, void* d_ws, size_t ws_size,
                              hipStream_t stream) {
  const float* x  = (const float*)d_in[0];
  const float* h  = (const float*)d_in[1];
  const float* fw = (const float*)d_in[2];
  const float* gw = (const float*)d_in[3];
  float* out = (float*)d_out;

  const size_t base  = 2ull * 1024 * 1024 + 8ull * 1024 * 1024;  // Q+K+V
  const size_t rows  = (size_t)NB * NROW;                        // 16384
  const size_t need4 = base + rows * 4 * 8 + rows * 4 * 512;
  const size_t need2 = base + rows * 2 * 8 + rows * 2 * 512;
  const size_t need1 = base + rows * 1 * 8 + rows * 1 * 512;
  const int split = (ws_size >= need4) ? 4 : (ws_size >= need2) ? 2
                    : (ws_size >= need1) ? 1 : 0;

  if (split) {
    ushort* Qw = (ushort*)d_ws;
    ushort* Kw = Qw + (1ull << 19);            // +1MB
    ushort* Vw = Kw + (1ull << 19);            // +1MB (V: 8MB)
    float*  pml  = (float*)((char*)d_ws + base);
    ushort* pacc = (ushort*)((char*)d_ws + base + rows * split * 8);

    proj_ws<<<dim3(512, 2), 256, 0, stream>>>(x, h, fw, gw, Qw, Kw);
    vprep<<<256, 256, 0, stream>>>(h, Vw);
    attn_split<<<256 * split, 256, 0, stream>>>(Qw, Kw, Vw, pml, pacc, split, 64 / split);
    reduce_concat<<<2048, 256, 0, stream>>>(pml, pacc, x, out, split);
  } else {
    proj_fb<<<dim3(512, 2), 256, 0, stream>>>(x, h, fw, gw, out);
    attn_fb<<<256, 256, 0, stream>>>(h, out);
    concat_fb<<<4096, 256, 0, stream>>>((const float4*)x, (float4*)out);
  }
}

// Round 3
// 110.810 us; speedup vs baseline: 2.1092x; 1.4111x over previous
//
#include <hip/hip_runtime.h>
#include <hip/hip_bf16.h>

#define NB   4
#define NROW 4096      // W*W
#define CIN  256
#define OUTC 512
#define DP   32

typedef __bf16 bf16x8 __attribute__((ext_vector_type(8)));
typedef float  f32x4  __attribute__((ext_vector_type(4)));
typedef ushort ushort8 __attribute__((ext_vector_type(8)));

__device__ __forceinline__ ushort f2bf(float x) {
  union { float f; unsigned u; } v; v.f = x;
  unsigned r = v.u + 0x7fffu + ((v.u >> 16) & 1u);   // RNE
  return (ushort)(r >> 16);
}

__device__ __forceinline__ uint pack2(float a, float b) {
  __hip_bfloat162 h = __float22bfloat162_rn(float2{a, b});  // v_cvt_pk_bf16_f32
  uint u; __builtin_memcpy(&u, &h, 4);
  return u;
}

__device__ __forceinline__ void gload_lds16(const void* g, void* l) {
  __builtin_amdgcn_global_load_lds(
      (const __attribute__((address_space(1))) unsigned int*)g,
      (__attribute__((address_space(3))) unsigned int*)l, 16, 0, 0);
}

// ===========================================================================
// SPLIT-K PATH
// ===========================================================================

// Projections -> bf16 Q/K in ws; which==1 blocks also emit V (bf16, transposed,
// tile-major, group-swizzled) from the h rows already staged in LDS.
__global__ __launch_bounds__(256) void proj_ws(
    const float* __restrict__ x, const float* __restrict__ h,
    const float* __restrict__ fw, const float* __restrict__ gw,
    ushort* __restrict__ Qb, ushort* __restrict__ Kb, ushort* __restrict__ Vw) {
  __shared__ float wl[8192];
  __shared__ float rows[8][260];
  const int t = threadIdx.x;
  const int which = blockIdx.y;
  const float* in = which ? h : x;
  const float* w  = which ? fw : gw;
  ushort* dst = which ? Kb : Qb;
  for (int i = t; i < 8192; i += 256) wl[i] = w[i];
  const int row0 = blockIdx.x * 32;
  const int d = t & 31, rl = t >> 5;
  for (int rp = 0; rp < 4; ++rp) {
    __syncthreads();
    for (int i = t; i < 2048; i += 256)
      rows[i >> 8][i & 255] = in[(long)(row0 + rp * 8 + (i >> 8)) * CIN + (i & 255)];
    __syncthreads();
    float a = 0.f;
#pragma unroll 8
    for (int c = 0; c < 256; ++c) a = fmaf(rows[rl][c], wl[c * 32 + d], a);
    dst[(long)(row0 + rp * 8 + rl) * DP + d] = f2bf(a);
    if (which) {   // V prep: thread t = channel, 8 keys (one swizzle group)
      const int rbase = row0 + rp * 8;
      const int b = rbase >> 12;
      const int tile = (rbase & 4095) >> 6;
      const int g = (rbase & 63) >> 3;
      ushort tmp[8];
#pragma unroll
      for (int j = 0; j < 8; ++j) tmp[j] = f2bf(rows[j][t]);
      *(ushort8*)(Vw + ((size_t)(b * 64 + tile) * 256 + t) * 64 + ((g ^ (t & 7)) << 3)) =
          *(const ushort8*)tmp;
    }
  }
}

// Flash attention, 8 waves (2 q-tiles of 64 rows) per block, split-K=4.
// Fragments (16x16x32 bf16, HW-verified r1/r2): A row=l&15,k=8*(l>>4)+j ;
// B col=l&15,k=8*(l>>4)+j ; D col=l&15,row=4*(l>>4)+reg.
// Swapped QK^T: st[kt][r] = S[q=lo][key=kt*16+4*hi+r]  (q is lane-local!)
// Transposed PV: acc[ct][r] = O^T[c=ct*16+4*hi+r][q=lo]
__global__ __launch_bounds__(512, 4) void attn8(
    const ushort* __restrict__ Qb, const ushort* __restrict__ Kb,
    const ushort* __restrict__ Vw, float* __restrict__ pml,
    ushort* __restrict__ pacc) {
  __shared__ ushort Vt[16384];   // 32KB [c][64 keys], group-swizzled g^(c&7)
  __shared__ uint   Pl[4096];    // 16KB, per-wave 512 dwords [q][32dw] swizzled

  const int t  = threadIdx.x;
  const int w  = t >> 6;
  const int l  = t & 63;
  const int lo = l & 15;
  const int hi = l >> 4;

  const int bid = blockIdx.x;           // XCD = (4b+s)&7 -> per-XCD K/V reuse
  const int s   = bid & 3;
  const int b   = (bid >> 2) & 3;
  const int qsb = bid >> 4;
  const int qrow = qsb * 128 + w * 16;
  const size_t rbase = (size_t)b * NROW;

  // Q as B-operand: lane holds Q[q=lo][d=8*hi+j]
  const bf16x8 qf = *(const bf16x8*)(Qb + (rbase + qrow + lo) * DP + hi * 8);

  f32x4 acc[16];
#pragma unroll
  for (int i = 0; i < 16; ++i) acc[i] = (f32x4){0.f, 0.f, 0.f, 0.f};
  float mrow = -1e30f, lsum = 0.f;

  uint* plw = Pl + w * 512;
  const int tI0 = s * 16;

  // prologue: stage tile 0, preload K fragments for tile 0
  {
    const ushort* src = Vw + (size_t)(b * 64 + tI0) * 16384;
#pragma unroll
    for (int i = 0; i < 4; ++i)
      gload_lds16(src + (w * 4 + i) * 512 + l * 8, &Vt[(w * 4 + i) * 512]);
  }
  bf16x8 kf[4];
#pragma unroll
  for (int kt = 0; kt < 4; ++kt)
    kf[kt] = *(const bf16x8*)(Kb + (rbase + tI0 * 64 + kt * 16 + lo) * DP + hi * 8);

  for (int tt = 0; tt < 16; ++tt) {
    const int tileIdx = tI0 + tt;

    // S^T = K Q^T : lane-local P row
    f32x4 st[4];
#pragma unroll
    for (int kt = 0; kt < 4; ++kt)
      st[kt] = __builtin_amdgcn_mfma_f32_16x16x32_bf16(
          kf[kt], qf, (f32x4){0.f, 0.f, 0.f, 0.f}, 0, 0, 0);

    // online softmax: in-lane max over 16, 2 shuffles across hi-groups
    float m4 = -1e30f;
#pragma unroll
    for (int kt = 0; kt < 4; ++kt)
#pragma unroll
      for (int r = 0; r < 4; ++r) m4 = fmaxf(m4, st[kt][r]);
    m4 = fmaxf(m4, __shfl_xor(m4, 16, 64));
    m4 = fmaxf(m4, __shfl_xor(m4, 32, 64));
    if (__any(m4 > mrow + 5.f)) {       // defer-max (T13, THR=5)
      const float mn = fmaxf(mrow, m4);
      const float alpha = __expf(mrow - mn);
      mrow = mn;
#pragma unroll
      for (int ct = 0; ct < 16; ++ct) acc[ct] *= alpha;
      lsum *= alpha;
    }
    float ps = 0.f;
#pragma unroll
    for (int kt = 0; kt < 4; ++kt)
#pragma unroll
      for (int r = 0; r < 4; ++r) {
        const float p = __expf(st[kt][r] - mrow);
        st[kt][r] = p;
        ps += p;
      }
    ps += __shfl_xor(ps, 16, 64);
    ps += __shfl_xor(ps, 32, 64);
    lsum += ps;

    // P^T -> LDS packed bf16x2, group-swizzled (g = key>>3, pos = g^(q&7))
#pragma unroll
    for (int kt = 0; kt < 4; ++kt)
#pragma unroll
      for (int pr = 0; pr < 2; ++pr) {
        const uint pd = pack2(st[kt][2 * pr], st[kt][2 * pr + 1]);
        plw[lo * 32 + ((((kt << 1) + (hi >> 1)) ^ (lo & 7)) << 2) +
            ((hi & 1) << 1) + pr] = pd;
      }

    __syncthreads();   // Vt(t) staged+visible; P writes ordered per-wave

    // prefetch K fragments for next tile (drained at next barrier, hidden by PV)
    const int tN = (tt < 15) ? tileIdx + 1 : tileIdx;
#pragma unroll
    for (int kt = 0; kt < 4; ++kt)
      kf[kt] = *(const bf16x8*)(Kb + (rbase + tN * 64 + kt * 16 + lo) * DP + hi * 8);

    // PV: acc^T += V^T(A) x P^T(B)
    const bf16x8 pb0 = *(const bf16x8*)&plw[lo * 32 + ((hi ^ (lo & 7)) << 2)];
    const bf16x8 pb1 = *(const bf16x8*)&plw[lo * 32 + (((hi + 4) ^ (lo & 7)) << 2)];
#pragma unroll
    for (int ct = 0; ct < 16; ++ct) {
      const int c = ct * 16 + lo;
      const bf16x8 v0 = *(const bf16x8*)&Vt[c * 64 + ((hi ^ (c & 7)) << 3)];
      const bf16x8 v1 = *(const bf16x8*)&Vt[c * 64 + (((hi + 4) ^ (c & 7)) << 3)];
      acc[ct] = __builtin_amdgcn_mfma_f32_16x16x32_bf16(v0, pb0, acc[ct], 0, 0, 0);
      acc[ct] = __builtin_amdgcn_mfma_f32_16x16x32_bf16(v1, pb1, acc[ct], 0, 0, 0);
    }

    __syncthreads();   // all waves done reading Vt(t)

    if (tt < 15) {     // stage next V tile (drains at next iter's barrier)
      const ushort* src = Vw + (size_t)(b * 64 + tileIdx + 1) * 16384;
#pragma unroll
      for (int i = 0; i < 4; ++i)
        gload_lds16(src + (w * 4 + i) * 512 + l * 8, &Vt[(w * 4 + i) * 512]);
    }
  }

  // partials: pacc bf16 [row][s][256] (acc is O^T: c = ct*16+4hi+r), pml f32
  const size_t prow = rbase + qrow + lo;
  if (hi == 0) {
    float* mlp = pml + (prow * 4 + s) * 2;
    mlp[0] = mrow;
    mlp[1] = lsum;
  }
  ushort* pr = pacc + (prow * 4 + s) * 256;
#pragma unroll
  for (int ct = 0; ct < 16; ++ct) {
    uint2 d;
    d.x = pack2(acc[ct][0], acc[ct][1]);
    d.y = pack2(acc[ct][2], acc[ct][3]);
    *(uint2*)&pr[ct * 16 + (hi << 2)] = d;
  }
}

// Combine partials + normalize -> out[...,0:256]; concat x -> out[...,256:512]
__global__ __launch_bounds__(256) void reduce_concat(
    const float* __restrict__ pml, const ushort* __restrict__ pacc,
    const float* __restrict__ x, float* __restrict__ out) {
  const int t = threadIdx.x;
  const int row = blockIdx.x * 8 + (t >> 5);
  const int c0 = (t & 31) * 8;

  float ms[4], ls[4];
  float m = -1e30f;
#pragma unroll
  for (int s = 0; s < 4; ++s) {
    ms[s] = pml[((size_t)row * 4 + s) * 2];
    ls[s] = pml[((size_t)row * 4 + s) * 2 + 1];
    m = fmaxf(m, ms[s]);
  }
  float L = 0.f, wgt[4];
#pragma unroll
  for (int s = 0; s < 4; ++s) {
    wgt[s] = __expf(ms[s] - m);
    L += wgt[s] * ls[s];
  }
  float o[8] = {0.f, 0.f, 0.f, 0.f, 0.f, 0.f, 0.f, 0.f};
#pragma unroll
  for (int s = 0; s < 4; ++s) {
    const bf16x8 a = *(const bf16x8*)(pacc + ((size_t)row * 4 + s) * 256 + c0);
    const float wg = wgt[s];
#pragma unroll
    for (int i = 0; i < 8; ++i) o[i] += wg * (float)a[i];
  }
  const float inv = 1.f / L;
  float4 o0 = {o[0] * inv, o[1] * inv, o[2] * inv, o[3] * inv};
  float4 o1 = {o[4] * inv, o[5] * inv, o[6] * inv, o[7] * inv};
  float4* op = (float4*)(out + (size_t)row * OUTC + c0);
  op[0] = o0; op[1] = o1;
  const float4* xp = (const float4*)(x + (size_t)row * CIN + c0);
  float4* oc = (float4*)(out + (size_t)row * OUTC + 256 + c0);
  oc[0] = xp[0]; oc[1] = xp[1];
}

// ===========================================================================
// FALLBACK PATH (round-1, no workspace) — used only if ws_size too small
// ===========================================================================
__global__ __launch_bounds__(256) void proj_fb(
    const float* __restrict__ x, const float* __restrict__ h,
    const float* __restrict__ fw, const float* __restrict__ gw,
    float* __restrict__ out) {
  __shared__ float wl[8192];
  __shared__ float rows[8][260];
  const int t = threadIdx.x;
  const int which = blockIdx.y;
  const float* in = which ? h : x;
  const float* w  = which ? fw : gw;
  for (int i = t; i < 8192; i += 256) wl[i] = w[i];
  const int row0 = blockIdx.x * 32;
  const int d = t & 31, rl = t >> 5;
  for (int rp = 0; rp < 4; ++rp) {
    __syncthreads();
    for (int i = t; i < 2048; i += 256)
      rows[i >> 8][i & 255] = in[(long)(row0 + rp * 8 + (i >> 8)) * CIN + (i & 255)];
    __syncthreads();
    float a = 0.f;
#pragma unroll 8
    for (int c = 0; c < 256; ++c) a = fmaf(rows[rl][c], wl[c * 32 + d], a);
    const long row = row0 + rp * 8 + rl;
    ((ushort*)(out + row * OUTC + 256))[which * 32 + d] = f2bf(a);
  }
}

__global__ __launch_bounds__(256) void attn_fb(
    const float* __restrict__ h, float* __restrict__ out) {
  __shared__ alignas(16) ushort Vt[256][72];
  __shared__ alignas(16) ushort Pl[4][16][72];
  const int t = threadIdx.x;
  const int w = t >> 6, l = t & 63, lo = l & 15, hi = l >> 4;
  const int bid = blockIdx.x;
  const int b = (bid >> 1) & 3;
  const int qb = ((bid >> 3) << 1) | (bid & 1);
  const int q0 = qb * 64;
  const long rowbase = (long)b * NROW;
  const ushort* gslot = (const ushort*)(out + (rowbase + q0 + w * 16 + lo) * OUTC + 256);
  const bf16x8 qf = *(const bf16x8*)(gslot + hi * 8);
  f32x4 acc[16];
#pragma unroll
  for (int i = 0; i < 16; ++i) acc[i] = (f32x4){0.f, 0.f, 0.f, 0.f};
  float mrow[4] = {-1e30f, -1e30f, -1e30f, -1e30f};
  float lsum[4] = {0.f, 0.f, 0.f, 0.f};
  for (int k0 = 0; k0 < NROW; k0 += 64) {
    bf16x8 kf[4];
#pragma unroll
    for (int kt = 0; kt < 4; ++kt) {
      const ushort* fslot =
          (const ushort*)(out + (rowbase + k0 + kt * 16 + lo) * OUTC + 256) + 32;
      kf[kt] = *(const bf16x8*)(fslot + hi * 8);
    }
    __syncthreads();
    {
      const float* hp = h + (rowbase + k0) * CIN + t;
#pragma unroll
      for (int g8 = 0; g8 < 8; ++g8) {
        ushort tmp[8];
#pragma unroll
        for (int i = 0; i < 8; ++i) tmp[i] = f2bf(hp[(g8 * 8 + i) * CIN]);
        *(bf16x8*)&Vt[t][g8 * 8] = *(const bf16x8*)tmp;
      }
    }
    __syncthreads();
    f32x4 sv[4];
#pragma unroll
    for (int kt = 0; kt < 4; ++kt)
      sv[kt] = __builtin_amdgcn_mfma_f32_16x16x32_bf16(
          qf, kf[kt], (f32x4){0.f, 0.f, 0.f, 0.f}, 0, 0, 0);
    float alpha[4];
    bool upd = false;
#pragma unroll
    for (int r = 0; r < 4; ++r) {
      float m4 = fmaxf(fmaxf(sv[0][r], sv[1][r]), fmaxf(sv[2][r], sv[3][r]));
#pragma unroll
      for (int off = 1; off < 16; off <<= 1) m4 = fmaxf(m4, __shfl_xor(m4, off, 64));
      const float mn = fmaxf(mrow[r], m4);
      alpha[r] = __expf(mrow[r] - mn);
      upd |= (mn > mrow[r]);
      mrow[r] = mn;
    }
    if (__any(upd)) {
#pragma unroll
      for (int ct = 0; ct < 16; ++ct)
#pragma unroll
        for (int r = 0; r < 4; ++r) acc[ct][r] *= alpha[r];
#pragma unroll
      for (int r = 0; r < 4; ++r) lsum[r] *= alpha[r];
    }
#pragma unroll
    for (int r = 0; r < 4; ++r) {
      float ps = 0.f;
#pragma unroll
      for (int kt = 0; kt < 4; ++kt) {
        const float p = __expf(sv[kt][r] - mrow[r]);
        sv[kt][r] = p;
        ps += p;
      }
#pragma unroll
      for (int off = 1; off < 16; off <<= 1) ps += __shfl_xor(ps, off, 64);
      lsum[r] += ps;
    }
#pragma unroll
    for (int kt = 0; kt < 4; ++kt)
#pragma unroll
      for (int r = 0; r < 4; ++r)
        Pl[w][hi * 4 + r][kt * 16 + lo] = f2bf(sv[kt][r]);
    asm volatile("s_waitcnt lgkmcnt(0)" ::: "memory");
    const bf16x8 pa0 = *(const bf16x8*)&Pl[w][lo][hi * 8];
    const bf16x8 pa1 = *(const bf16x8*)&Pl[w][lo][32 + hi * 8];
#pragma unroll
    for (int ct = 0; ct < 16; ++ct) {
      const bf16x8 v0 = *(const bf16x8*)&Vt[ct * 16 + lo][hi * 8];
      const bf16x8 v1 = *(const bf16x8*)&Vt[ct * 16 + lo][32 + hi * 8];
      acc[ct] = __builtin_amdgcn_mfma_f32_16x16x32_bf16(pa0, v0, acc[ct], 0, 0, 0);
      acc[ct] = __builtin_amdgcn_mfma_f32_16x16x32_bf16(pa1, v1, acc[ct], 0, 0, 0);
    }
  }
#pragma unroll
  for (int r = 0; r < 4; ++r) {
    const float inv = 1.f / lsum[r];
    float* orow = out + (rowbase + q0 + w * 16 + hi * 4 + r) * OUTC;
#pragma unroll
    for (int ct = 0; ct < 16; ++ct) orow[ct * 16 + lo] = acc[ct][r] * inv;
  }
}

__global__ __launch_bounds__(256) void concat_fb(
    const float4* __restrict__ x, float4* __restrict__ out) {
  const int idx = blockIdx.x * 256 + threadIdx.x;
  const int row = idx >> 6, c4 = idx & 63;
  out[row * 128 + 64 + c4] = x[idx];
}

// ===========================================================================
extern "C" void kernel_launch(void* const* d_in, const int* in_sizes, int n_in,
                              void* d_out, int out_size, void* d_ws, size_t ws_size,
                              hipStream_t stream) {
  const float* x  = (const float*)d_in[0];
  const float* h  = (const float*)d_in[1];
  const float* fw = (const float*)d_in[2];
  const float* gw = (const float*)d_in[3];
  float* out = (float*)d_out;

  const size_t rows = (size_t)NB * NROW;                      // 16384
  const size_t base = 10ull * 1024 * 1024;                    // Q(1)+K(1)+V(8)
  const size_t need = base + rows * 4 * 8 + rows * 4 * 512;   // pml + pacc

  if (ws_size >= need) {
    ushort* Qw = (ushort*)d_ws;
    ushort* Kw = Qw + (1ull << 19);            // +1MB
    ushort* Vw = Kw + (1ull << 19);            // +1MB (V: 8MB)
    float*  pml  = (float*)((char*)d_ws + base);
    ushort* pacc = (ushort*)((char*)d_ws + base + rows * 4 * 8);

    proj_ws<<<dim3(512, 2), 256, 0, stream>>>(x, h, fw, gw, Qw, Kw, Vw);
    attn8<<<512, 512, 0, stream>>>(Qw, Kw, Vw, pml, pacc);
    reduce_concat<<<2048, 256, 0, stream>>>(pml, pacc, x, out);
  } else {
    proj_fb<<<dim3(512, 2), 256, 0, stream>>>(x, h, fw, gw, out);
    attn_fb<<<256, 256, 0, stream>>>(h, out);
    concat_fb<<<4096, 256, 0, stream>>>((const float4*)x, (float4*)out);
  }
}

// Round 4
// 86.462 us; speedup vs baseline: 2.7032x; 1.2816x over previous
//
#include <hip/hip_runtime.h>
#include <hip/hip_bf16.h>

#define NB   4
#define NROW 4096      // W*W
#define CIN  256
#define OUTC 512
#define DP   32

typedef __bf16 bf16x8 __attribute__((ext_vector_type(8)));
typedef float  f32x4  __attribute__((ext_vector_type(4)));
typedef ushort ushort8 __attribute__((ext_vector_type(8)));

__device__ __forceinline__ ushort f2bf(float x) {
  union { float f; unsigned u; } v; v.f = x;
  unsigned r = v.u + 0x7fffu + ((v.u >> 16) & 1u);   // RNE
  return (ushort)(r >> 16);
}

__device__ __forceinline__ uint pack2(float a, float b) {
  __hip_bfloat162 h = __float22bfloat162_rn(float2{a, b});  // v_cvt_pk_bf16_f32
  uint u; __builtin_memcpy(&u, &h, 4);
  return u;
}

__device__ __forceinline__ void gload_lds16(const void* g, void* l) {
  __builtin_amdgcn_global_load_lds(
      (const __attribute__((address_space(1))) unsigned int*)g,
      (__attribute__((address_space(3))) unsigned int*)l, 16, 0, 0);
}

// ===========================================================================
// SPLIT-K PATH
// ===========================================================================

// MFMA projection: block = 64 rows. which==0: g = x@g_w -> Qb;
// which==1: f = h@f_w -> Kb, plus V (bf16, transposed, tile-major, swizzled).
// A staged bf16 in LDS with 16B-slot XOR swizzle: element (r,c) lives at
// ushort index r*256 + (((c>>3)^(r&7))<<3) + (c&7).
__global__ __launch_bounds__(256) void proj_mfma(
    const float* __restrict__ x, const float* __restrict__ h,
    const float* __restrict__ fw, const float* __restrict__ gw,
    ushort* __restrict__ Qb, ushort* __restrict__ Kb, ushort* __restrict__ Vw) {
  __shared__ ushort Ab[64 * 256];   // 32KB swizzled rows
  __shared__ ushort Wt[32 * 256];   // 16KB W^T [d][k] linear
  const int t = threadIdx.x;
  const int which = blockIdx.y;
  const float* in   = which ? h : x;
  const float* wsrc = which ? fw : gw;
  ushort* dst = which ? Kb : Qb;
  const int row0 = blockIdx.x * 64;

  {  // stage A: coalesced float4 reads, 8B swizzled LDS writes
    const float4* inp = (const float4*)(in + (size_t)row0 * CIN);
#pragma unroll
    for (int i = 0; i < 16; ++i) {
      const int idx = i * 256 + t;
      const int r = idx >> 6;
      const int c = (idx & 63) * 4;
      const float4 v = inp[idx];
      ushort tmp[4] = {f2bf(v.x), f2bf(v.y), f2bf(v.z), f2bf(v.w)};
      const int slot = (c >> 3) ^ (r & 7);
      *(uint2*)&Ab[r * 256 + (slot << 3) + (c & 7)] = *(const uint2*)tmp;
    }
  }
  {  // stage W^T (tiny, L2-hot)
    const int d = t & 31;
    const int k0 = (t >> 5) * 32;
#pragma unroll 8
    for (int j = 0; j < 32; ++j)
      Wt[d * 256 + k0 + j] = f2bf(wsrc[(size_t)(k0 + j) * DP + d]);
  }
  __syncthreads();

  const int w = t >> 6, l = t & 63, lo = l & 15, hi = l >> 4;
  f32x4 acc[2];
  acc[0] = (f32x4){0.f, 0.f, 0.f, 0.f};
  acc[1] = (f32x4){0.f, 0.f, 0.f, 0.f};
  const int R = w * 16 + lo;          // A-row this lane supplies
#pragma unroll
  for (int kk = 0; kk < 8; ++kk) {
    const int slot = (kk * 4 + hi) ^ (R & 7);
    const bf16x8 a = *(const bf16x8*)&Ab[R * 256 + (slot << 3)];
#pragma unroll
    for (int nt = 0; nt < 2; ++nt) {
      const bf16x8 bfr = *(const bf16x8*)&Wt[(nt * 16 + lo) * 256 + kk * 32 + hi * 8];
      acc[nt] = __builtin_amdgcn_mfma_f32_16x16x32_bf16(a, bfr, acc[nt], 0, 0, 0);
    }
  }
  // D: row = 4*hi + r (projected row), col = lo (output channel)
#pragma unroll
  for (int nt = 0; nt < 2; ++nt)
#pragma unroll
    for (int r = 0; r < 4; ++r)
      dst[(size_t)(row0 + w * 16 + hi * 4 + r) * DP + nt * 16 + lo] = f2bf(acc[nt][r]);

  if (which) {  // V: column-gather from swizzled Ab, swizzled 16B global writes
    const int b = row0 >> 12;
    const int tile = (row0 & 4095) >> 6;
    const int c = t;
    ushort* vdst = Vw + ((size_t)(b * 64 + tile) * 256 + c) * 64;
#pragma unroll
    for (int g = 0; g < 8; ++g) {
      ushort tmp[8];
#pragma unroll
      for (int j = 0; j < 8; ++j) {
        const int slot = (c >> 3) ^ j;     // row = 8g+j -> row&7 = j
        tmp[j] = Ab[(8 * g + j) * 256 + (slot << 3) + (c & 7)];
      }
      *(ushort8*)(vdst + ((g ^ (c & 7)) << 3)) = *(const ushort8*)tmp;
    }
  }
}

// Flash attention, 8 waves (2 q-tiles of 64 rows) per block, split-K=4.
// Double-buffered Vt, ONE barrier per tile. Fragments (16x16x32 bf16):
// A row=l&15,k=8*(l>>4)+j ; B col=l&15,k=8*(l>>4)+j ; D col=l&15,row=4*(l>>4)+reg.
// Swapped QK^T: st[kt][r] = S[q=lo][key=kt*16+4*hi+r]  (q lane-local)
// Transposed PV: acc[ct][r] = O^T[c=ct*16+4*hi+r][q=lo]
__global__ __launch_bounds__(512, 4) void attn8(
    const ushort* __restrict__ Qb, const ushort* __restrict__ Kb,
    const ushort* __restrict__ Vw, float* __restrict__ pml,
    ushort* __restrict__ pacc) {
  __shared__ ushort Vt[2][16384];  // 64KB double-buffered [c][64 keys], g^(c&7)
  __shared__ uint   Pl[4096];      // 16KB per-wave 512 dwords, swizzled

  const int t  = threadIdx.x;
  const int w  = t >> 6;
  const int l  = t & 63;
  const int lo = l & 15;
  const int hi = l >> 4;

  const int bid = blockIdx.x;           // XCD = (4b+s)&7 -> per-XCD K/V reuse
  const int s   = bid & 3;
  const int b   = (bid >> 2) & 3;
  const int qsb = bid >> 4;
  const int qrow = qsb * 128 + w * 16;
  const size_t rbase = (size_t)b * NROW;

  const bf16x8 qf = *(const bf16x8*)(Qb + (rbase + qrow + lo) * DP + hi * 8);

  f32x4 acc[16];
#pragma unroll
  for (int i = 0; i < 16; ++i) acc[i] = (f32x4){0.f, 0.f, 0.f, 0.f};
  float mrow = -1e30f, lsum = 0.f;

  uint* plw = Pl + w * 512;
  const int tI0 = s * 16;

  // prologue: stage tile 0 into buf0, preload K fragments, drain
  {
    const ushort* src = Vw + (size_t)(b * 64 + tI0) * 16384;
#pragma unroll
    for (int i = 0; i < 4; ++i)
      gload_lds16(src + (w * 4 + i) * 512 + l * 8, &Vt[0][(w * 4 + i) * 512]);
  }
  bf16x8 kf[4];
#pragma unroll
  for (int kt = 0; kt < 4; ++kt)
    kf[kt] = *(const bf16x8*)(Kb + (rbase + tI0 * 64 + kt * 16 + lo) * DP + hi * 8);
  __syncthreads();
  int cur = 0;

  for (int tt = 0; tt < 16; ++tt) {
    const int tileIdx = tI0 + tt;

    // issue stage of NEXT tile into the other buffer (drains at the barrier)
    if (tt < 15) {
      const ushort* src = Vw + (size_t)(b * 64 + tileIdx + 1) * 16384;
#pragma unroll
      for (int i = 0; i < 4; ++i)
        gload_lds16(src + (w * 4 + i) * 512 + l * 8, &Vt[cur ^ 1][(w * 4 + i) * 512]);
    }

    // S^T = K Q^T : lane-local P row
    f32x4 st[4];
#pragma unroll
    for (int kt = 0; kt < 4; ++kt)
      st[kt] = __builtin_amdgcn_mfma_f32_16x16x32_bf16(
          kf[kt], qf, (f32x4){0.f, 0.f, 0.f, 0.f}, 0, 0, 0);

    // online softmax (hides the stage latency)
    float m4 = -1e30f;
#pragma unroll
    for (int kt = 0; kt < 4; ++kt)
#pragma unroll
      for (int r = 0; r < 4; ++r) m4 = fmaxf(m4, st[kt][r]);
    m4 = fmaxf(m4, __shfl_xor(m4, 16, 64));
    m4 = fmaxf(m4, __shfl_xor(m4, 32, 64));
    if (__any(m4 > mrow + 5.f)) {       // defer-max (T13, THR=5)
      const float mn = fmaxf(mrow, m4);
      const float alpha = __expf(mrow - mn);
      mrow = mn;
#pragma unroll
      for (int ct = 0; ct < 16; ++ct) acc[ct] *= alpha;
      lsum *= alpha;
    }
    float ps = 0.f;
#pragma unroll
    for (int kt = 0; kt < 4; ++kt)
#pragma unroll
      for (int r = 0; r < 4; ++r) {
        const float p = __expf(st[kt][r] - mrow);
        st[kt][r] = p;
        ps += p;
      }
    ps += __shfl_xor(ps, 16, 64);
    ps += __shfl_xor(ps, 32, 64);
    lsum += ps;

    // P^T -> LDS packed bf16x2 (per-wave private; lgkmcnt ordering only)
#pragma unroll
    for (int kt = 0; kt < 4; ++kt)
#pragma unroll
      for (int pr = 0; pr < 2; ++pr) {
        const uint pd = pack2(st[kt][2 * pr], st[kt][2 * pr + 1]);
        plw[lo * 32 + ((((kt << 1) + (hi >> 1)) ^ (lo & 7)) << 2) +
            ((hi & 1) << 1) + pr] = pd;
      }

    // prefetch K fragments for next tile (used after the barrier)
    const int tN = (tt < 15) ? tileIdx + 1 : tileIdx;
#pragma unroll
    for (int kt = 0; kt < 4; ++kt)
      kf[kt] = *(const bf16x8*)(Kb + (rbase + tN * 64 + kt * 16 + lo) * DP + hi * 8);

    // PV from current buffer
    const bf16x8 pb0 = *(const bf16x8*)&plw[lo * 32 + ((hi ^ (lo & 7)) << 2)];
    const bf16x8 pb1 = *(const bf16x8*)&plw[lo * 32 + (((hi + 4) ^ (lo & 7)) << 2)];
    const ushort* vb = Vt[cur];
    __builtin_amdgcn_s_setprio(1);
#pragma unroll
    for (int ct = 0; ct < 16; ++ct) {
      const int c = ct * 16 + lo;
      const bf16x8 v0 = *(const bf16x8*)&vb[c * 64 + ((hi ^ (c & 7)) << 3)];
      const bf16x8 v1 = *(const bf16x8*)&vb[c * 64 + (((hi + 4) ^ (c & 7)) << 3)];
      acc[ct] = __builtin_amdgcn_mfma_f32_16x16x32_bf16(v0, pb0, acc[ct], 0, 0, 0);
      acc[ct] = __builtin_amdgcn_mfma_f32_16x16x32_bf16(v1, pb1, acc[ct], 0, 0, 0);
    }
    __builtin_amdgcn_s_setprio(0);

    __syncthreads();   // drains stage (vmcnt) + keeps buffers coherent
    cur ^= 1;
  }

  // partials: pacc bf16 [row][s][256] (acc is O^T: c = ct*16+4hi+r), pml f32
  const size_t prow = rbase + qrow + lo;
  if (hi == 0) {
    float* mlp = pml + (prow * 4 + s) * 2;
    mlp[0] = mrow;
    mlp[1] = lsum;
  }
  ushort* pr = pacc + (prow * 4 + s) * 256;
#pragma unroll
  for (int ct = 0; ct < 16; ++ct) {
    uint2 d;
    d.x = pack2(acc[ct][0], acc[ct][1]);
    d.y = pack2(acc[ct][2], acc[ct][3]);
    *(uint2*)&pr[ct * 16 + (hi << 2)] = d;
  }
}

// Combine partials + normalize -> out[...,0:256]; concat x -> out[...,256:512]
__global__ __launch_bounds__(256) void reduce_concat(
    const float* __restrict__ pml, const ushort* __restrict__ pacc,
    const float* __restrict__ x, float* __restrict__ out) {
  const int t = threadIdx.x;
  const int row = blockIdx.x * 8 + (t >> 5);
  const int c0 = (t & 31) * 8;

  float ms[4], ls[4];
  float m = -1e30f;
#pragma unroll
  for (int s = 0; s < 4; ++s) {
    ms[s] = pml[((size_t)row * 4 + s) * 2];
    ls[s] = pml[((size_t)row * 4 + s) * 2 + 1];
    m = fmaxf(m, ms[s]);
  }
  float L = 0.f, wgt[4];
#pragma unroll
  for (int s = 0; s < 4; ++s) {
    wgt[s] = __expf(ms[s] - m);
    L += wgt[s] * ls[s];
  }
  float o[8] = {0.f, 0.f, 0.f, 0.f, 0.f, 0.f, 0.f, 0.f};
#pragma unroll
  for (int s = 0; s < 4; ++s) {
    const bf16x8 a = *(const bf16x8*)(pacc + ((size_t)row * 4 + s) * 256 + c0);
    const float wg = wgt[s];
#pragma unroll
    for (int i = 0; i < 8; ++i) o[i] += wg * (float)a[i];
  }
  const float inv = 1.f / L;
  float4 o0 = {o[0] * inv, o[1] * inv, o[2] * inv, o[3] * inv};
  float4 o1 = {o[4] * inv, o[5] * inv, o[6] * inv, o[7] * inv};
  float4* op = (float4*)(out + (size_t)row * OUTC + c0);
  op[0] = o0; op[1] = o1;
  const float4* xp = (const float4*)(x + (size_t)row * CIN + c0);
  float4* oc = (float4*)(out + (size_t)row * OUTC + 256 + c0);
  oc[0] = xp[0]; oc[1] = xp[1];
}

// ===========================================================================
// FALLBACK PATH (round-1, no workspace) — used only if ws_size too small
// ===========================================================================
__global__ __launch_bounds__(256) void proj_fb(
    const float* __restrict__ x, const float* __restrict__ h,
    const float* __restrict__ fw, const float* __restrict__ gw,
    float* __restrict__ out) {
  __shared__ float wl[8192];
  __shared__ float rows[8][260];
  const int t = threadIdx.x;
  const int which = blockIdx.y;
  const float* in = which ? h : x;
  const float* w  = which ? fw : gw;
  for (int i = t; i < 8192; i += 256) wl[i] = w[i];
  const int row0 = blockIdx.x * 32;
  const int d = t & 31, rl = t >> 5;
  for (int rp = 0; rp < 4; ++rp) {
    __syncthreads();
    for (int i = t; i < 2048; i += 256)
      rows[i >> 8][i & 255] = in[(long)(row0 + rp * 8 + (i >> 8)) * CIN + (i & 255)];
    __syncthreads();
    float a = 0.f;
#pragma unroll 8
    for (int c = 0; c < 256; ++c) a = fmaf(rows[rl][c], wl[c * 32 + d], a);
    const long row = row0 + rp * 8 + rl;
    ((ushort*)(out + row * OUTC + 256))[which * 32 + d] = f2bf(a);
  }
}

__global__ __launch_bounds__(256) void attn_fb(
    const float* __restrict__ h, float* __restrict__ out) {
  __shared__ alignas(16) ushort Vt[256][72];
  __shared__ alignas(16) ushort Pl[4][16][72];
  const int t = threadIdx.x;
  const int w = t >> 6, l = t & 63, lo = l & 15, hi = l >> 4;
  const int bid = blockIdx.x;
  const int b = (bid >> 1) & 3;
  const int qb = ((bid >> 3) << 1) | (bid & 1);
  const int q0 = qb * 64;
  const long rowbase = (long)b * NROW;
  const ushort* gslot = (const ushort*)(out + (rowbase + q0 + w * 16 + lo) * OUTC + 256);
  const bf16x8 qf = *(const bf16x8*)(gslot + hi * 8);
  f32x4 acc[16];
#pragma unroll
  for (int i = 0; i < 16; ++i) acc[i] = (f32x4){0.f, 0.f, 0.f, 0.f};
  float mrow[4] = {-1e30f, -1e30f, -1e30f, -1e30f};
  float lsum[4] = {0.f, 0.f, 0.f, 0.f};
  for (int k0 = 0; k0 < NROW; k0 += 64) {
    bf16x8 kf[4];
#pragma unroll
    for (int kt = 0; kt < 4; ++kt) {
      const ushort* fslot =
          (const ushort*)(out + (rowbase + k0 + kt * 16 + lo) * OUTC + 256) + 32;
      kf[kt] = *(const bf16x8*)(fslot + hi * 8);
    }
    __syncthreads();
    {
      const float* hp = h + (rowbase + k0) * CIN + t;
#pragma unroll
      for (int g8 = 0; g8 < 8; ++g8) {
        ushort tmp[8];
#pragma unroll
        for (int i = 0; i < 8; ++i) tmp[i] = f2bf(hp[(g8 * 8 + i) * CIN]);
        *(bf16x8*)&Vt[t][g8 * 8] = *(const bf16x8*)tmp;
      }
    }
    __syncthreads();
    f32x4 sv[4];
#pragma unroll
    for (int kt = 0; kt < 4; ++kt)
      sv[kt] = __builtin_amdgcn_mfma_f32_16x16x32_bf16(
          qf, kf[kt], (f32x4){0.f, 0.f, 0.f, 0.f}, 0, 0, 0);
    float alpha[4];
    bool upd = false;
#pragma unroll
    for (int r = 0; r < 4; ++r) {
      float m4 = fmaxf(fmaxf(sv[0][r], sv[1][r]), fmaxf(sv[2][r], sv[3][r]));
#pragma unroll
      for (int off = 1; off < 16; off <<= 1) m4 = fmaxf(m4, __shfl_xor(m4, off, 64));
      const float mn = fmaxf(mrow[r], m4);
      alpha[r] = __expf(mrow[r] - mn);
      upd |= (mn > mrow[r]);
      mrow[r] = mn;
    }
    if (__any(upd)) {
#pragma unroll
      for (int ct = 0; ct < 16; ++ct)
#pragma unroll
        for (int r = 0; r < 4; ++r) acc[ct][r] *= alpha[r];
#pragma unroll
      for (int r = 0; r < 4; ++r) lsum[r] *= alpha[r];
    }
#pragma unroll
    for (int r = 0; r < 4; ++r) {
      float ps = 0.f;
#pragma unroll
      for (int kt = 0; kt < 4; ++kt) {
        const float p = __expf(sv[kt][r] - mrow[r]);
        sv[kt][r] = p;
        ps += p;
      }
#pragma unroll
      for (int off = 1; off < 16; off <<= 1) ps += __shfl_xor(ps, off, 64);
      lsum[r] += ps;
    }
#pragma unroll
    for (int kt = 0; kt < 4; ++kt)
#pragma unroll
      for (int r = 0; r < 4; ++r)
        Pl[w][hi * 4 + r][kt * 16 + lo] = f2bf(sv[kt][r]);
    asm volatile("s_waitcnt lgkmcnt(0)" ::: "memory");
    const bf16x8 pa0 = *(const bf16x8*)&Pl[w][lo][hi * 8];
    const bf16x8 pa1 = *(const bf16x8*)&Pl[w][lo][32 + hi * 8];
#pragma unroll
    for (int ct = 0; ct < 16; ++ct) {
      const bf16x8 v0 = *(const bf16x8*)&Vt[ct * 16 + lo][hi * 8];
      const bf16x8 v1 = *(const bf16x8*)&Vt[ct * 16 + lo][32 + hi * 8];
      acc[ct] = __builtin_amdgcn_mfma_f32_16x16x32_bf16(pa0, v0, acc[ct], 0, 0, 0);
      acc[ct] = __builtin_amdgcn_mfma_f32_16x16x32_bf16(pa1, v1, acc[ct], 0, 0, 0);
    }
  }
#pragma unroll
  for (int r = 0; r < 4; ++r) {
    const float inv = 1.f / lsum[r];
    float* orow = out + (rowbase + q0 + w * 16 + hi * 4 + r) * OUTC;
#pragma unroll
    for (int ct = 0; ct < 16; ++ct) orow[ct * 16 + lo] = acc[ct][r] * inv;
  }
}

__global__ __launch_bounds__(256) void concat_fb(
    const float4* __restrict__ x, float4* __restrict__ out) {
  const int idx = blockIdx.x * 256 + threadIdx.x;
  const int row = idx >> 6, c4 = idx & 63;
  out[row * 128 + 64 + c4] = x[idx];
}

// ===========================================================================
extern "C" void kernel_launch(void* const* d_in, const int* in_sizes, int n_in,
                              void* d_out, int out_size, void* d_ws, size_t ws_size,
                              hipStream_t stream) {
  const float* x  = (const float*)d_in[0];
  const float* h  = (const float*)d_in[1];
  const float* fw = (const float*)d_in[2];
  const float* gw = (const float*)d_in[3];
  float* out = (float*)d_out;

  const size_t rows = (size_t)NB * NROW;                      // 16384
  const size_t base = 10ull * 1024 * 1024;                    // Q(1)+K(1)+V(8)
  const size_t need = base + rows * 4 * 8 + rows * 4 * 512;   // pml + pacc

  if (ws_size >= need) {
    ushort* Qw = (ushort*)d_ws;
    ushort* Kw = Qw + (1ull << 19);            // +1MB
    ushort* Vw = Kw + (1ull << 19);            // +1MB (V: 8MB)
    float*  pml  = (float*)((char*)d_ws + base);
    ushort* pacc = (ushort*)((char*)d_ws + base + rows * 4 * 8);

    proj_mfma<<<dim3(256, 2), 256, 0, stream>>>(x, h, fw, gw, Qw, Kw, Vw);
    attn8<<<512, 512, 0, stream>>>(Qw, Kw, Vw, pml, pacc);
    reduce_concat<<<2048, 256, 0, stream>>>(pml, pacc, x, out);
  } else {
    proj_fb<<<dim3(512, 2), 256, 0, stream>>>(x, h, fw, gw, out);
    attn_fb<<<256, 256, 0, stream>>>(h, out);
    concat_fb<<<4096, 256, 0, stream>>>((const float4*)x, (float4*)out);
  }
}